// Round 3
// baseline (295.212 us; speedup 1.0000x reference)
//
#include <hip/hip_runtime.h>
#include <hip/hip_bf16.h>
#include <cstddef>
#include <cstdint>

#define B_SZ   8
#define T_CTX  1024
#define C_DIM  1024
#define H_NUM  16
#define HS     64
#define M_ROWS (B_SZ * T_CTX)

typedef __attribute__((ext_vector_type(8))) short bf16x8;
typedef __attribute__((ext_vector_type(8))) unsigned short u16x8;
typedef __attribute__((ext_vector_type(4))) float f32x4;

static __device__ inline unsigned short f2bf(float f) {
    __hip_bfloat16 h = __float2bfloat16(f);
    return __builtin_bit_cast(unsigned short, h);
}
static __device__ inline float bf2f(unsigned short u) {
    unsigned int v = ((unsigned int)u) << 16;
    return __builtin_bit_cast(float, v);
}
static __device__ inline void gld16(const void* g, void* l) {
    __builtin_amdgcn_global_load_lds((const __attribute__((address_space(1))) void*)g,
                                     (__attribute__((address_space(3))) void*)l,
                                     16, 0, 0);
}

// ---------------------------------------------------------------------------
// Fused conversion: blocks [0,8192) do x->xs (bf16, time-shifted);
// blocks [8192,12288) do the 4 weight matrices -> stacked bf16.
// ---------------------------------------------------------------------------
__global__ __launch_bounds__(256)
void convert_all(const float* __restrict__ x, unsigned short* __restrict__ xs,
                 const float* __restrict__ Wk, const float* __restrict__ Wv,
                 const float* __restrict__ Wr, const float* __restrict__ Wo,
                 unsigned short* __restrict__ wdst)
{
    const int bid = blockIdx.x;
    if (bid < 8192) {
        const int idx = (bid * 256 + threadIdx.x) * 4;
        const int m = idx >> 10;
        const int c = idx & 1023;
        float4 v;
        if (c < 512) {
            const int t = m & (T_CTX - 1);
            if (t == 0) v = make_float4(0.f, 0.f, 0.f, 0.f);
            else        v = *(const float4*)(x + (size_t)(m - 1) * C_DIM + c);
        } else {
            v = *(const float4*)(x + idx);
        }
        ushort4 o;
        o.x = f2bf(v.x); o.y = f2bf(v.y); o.z = f2bf(v.z); o.w = f2bf(v.w);
        *(ushort4*)(xs + idx) = o;
    } else {
        const int wid = bid - 8192;
        const int z = wid >> 10;
        const float* src = (z == 0) ? Wk : (z == 1) ? Wv : (z == 2) ? Wr : Wo;
        const int idx = ((wid & 1023) * 256 + threadIdx.x) * 4;
        const float4 v = *(const float4*)(src + idx);
        ushort4 o;
        o.x = f2bf(v.x); o.y = f2bf(v.y); o.z = f2bf(v.z); o.w = f2bf(v.w);
        *(ushort4*)(wdst + (size_t)z * (C_DIM * C_DIM) + idx) = o;
    }
}

// ---------------------------------------------------------------------------
// 256x256 8-phase pipelined bf16 MFMA GEMM (T1+T2+T3+T4+T5).
// 8 waves (2Mx4N), per-wave output 128x64, BK=64 split into 2 k-halves.
// LDS: per operand a ring of 4 half-slots [256 rows][32 k] (16 KB each),
// 128 KiB total -> 1 block/CU; overlap comes from counted vmcnt, not TLP.
// Per K-tile, 4 phases (ks,oh): each phase {ds_read frags; stage 1 future
// half-slot; lgkmcnt(0); 16 MFMA (setprio-wrapped); s_barrier}.
// Stage stream: p0:A(kt+1,1) p1:B(kt+1,1) p2:A(kt+2,0) p3:B(kt+2,0);
// single vmcnt(4) at p0 forces all of (kt,*) complete while leaving the
// next K-tile's ks0 pair (4 loads) in flight across the barriers.
// Swizzle: phys 16B chunk of row = log ^ ((row>>1)&3): frag reads 2-way
// bank aliasing (free); staged via pre-swizzled global source (gld16 dest
// must stay linear).
// Epilogue fused per z (n0>>10): 0 exp(clip)->fp32, 1 id->bf16, 2 sigmoid->bf16.
// ---------------------------------------------------------------------------
__global__ __launch_bounds__(512, 2)
void mfma_gemm256(const unsigned short* __restrict__ A,
                  const unsigned short* __restrict__ Wb,
                  const float* __restrict__ b0, const float* __restrict__ b1,
                  const float* __restrict__ b2,
                  void* __restrict__ o0, void* __restrict__ o1, void* __restrict__ o2)
{
    // 384 blocks = 32 ty x 12 tx; XCD-chunked: each XCD gets 4 ty rows x all tx
    const int d = blockIdx.x;
    const int g = (d & 7) * 48 + (d >> 3);
    const int ty = g / 12, tx = g - ty * 12;
    const int m0 = ty * 256, n0 = tx * 256;
    const int z = n0 >> 10;
    const int ncol0 = n0 & 1023;
    const float* bias = (z == 0) ? b0 : (z == 1) ? b1 : b2;
    void* out = (z == 0) ? o0 : (z == 1) ? o1 : o2;

    __shared__ unsigned short Ash[4 * 8192];   // 4 half-slots x 16 KB
    __shared__ unsigned short Bsh[4 * 8192];

    const int tid = threadIdx.x;
    const int w = tid >> 6, l = tid & 63;

    // ---- staging geometry (pre-swizzled global source, linear LDS dest) ----
    const int lrow = l >> 2;                         // 16 rows per 1KB instr
    const int lchk = (((l & 3) ^ ((l >> 3) & 3)) * 8);
    const unsigned short* gAs = A  + (size_t)(m0 + w * 32 + lrow) * C_DIM + lchk;
    const unsigned short* gBs = Wb + (size_t)(n0 + w * 32 + lrow) * C_DIM + lchk;
    unsigned short* const dA = Ash + w * 1024;       // wave-uniform dest base
    unsigned short* const dB = Bsh + w * 1024;

    auto stA = [&](int kt, int ks, int s) {
        const unsigned short* p = gAs + kt * 64 + ks * 32;
        gld16(p,              dA + s * 8192);
        gld16(p + 16 * C_DIM, dA + s * 8192 + 512);
    };
    auto stB = [&](int kt, int ks, int s) {
        const unsigned short* p = gBs + kt * 64 + ks * 32;
        gld16(p,              dB + s * 8192);
        gld16(p + 16 * C_DIM, dB + s * 8192 + 512);
    };

    // ---- fragment geometry ----
    const int wr = w >> 2, wc = w & 3;               // 2 x 4 wave grid
    const int lr = l & 15, lkq = l >> 4;
    const int cw = (lkq ^ ((lr >> 1) & 3)) * 16;     // swizzled chunk (bytes)
    const int abase = (wr * 128 + lr) * 64 + cw;     // byte offset in A slot
    const int bbase = (wc * 64 + lr) * 64 + cw;      // byte offset in B slot
    const char* const Ac = (const char*)Ash;
    const char* const Bc = (const char*)Bsh;

    bf16x8 af[4], bfr[4];
    auto ldA = [&](int s, int oh) {
        const char* base = Ac + s * 16384 + abase + oh * 4096;
        af[0] = *(const bf16x8*)(base);
        af[1] = *(const bf16x8*)(base + 1024);
        af[2] = *(const bf16x8*)(base + 2048);
        af[3] = *(const bf16x8*)(base + 3072);
    };
    auto ldB = [&](int s) {
        const char* base = Bc + s * 16384 + bbase;
        bfr[0] = *(const bf16x8*)(base);
        bfr[1] = *(const bf16x8*)(base + 1024);
        bfr[2] = *(const bf16x8*)(base + 2048);
        bfr[3] = *(const bf16x8*)(base + 3072);
    };

    f32x4 acc[8][4];
    #pragma unroll
    for (int i = 0; i < 8; ++i)
        #pragma unroll
        for (int j = 0; j < 4; ++j) acc[i][j] = (f32x4){0.f, 0.f, 0.f, 0.f};

    auto mm = [&](int mb) {
        __builtin_amdgcn_s_setprio(1);
        #pragma unroll
        for (int mi = 0; mi < 4; ++mi)
            #pragma unroll
            for (int j = 0; j < 4; ++j)
                acc[mb + mi][j] = __builtin_amdgcn_mfma_f32_16x16x32_bf16(
                    af[mi], bfr[j], acc[mb + mi][j], 0, 0, 0);
        __builtin_amdgcn_s_setprio(0);
    };

    // ---- prologue: (0,0) (0,1) (1,0) halves -> slots 0,1,2 (12 loads) ----
    stA(0, 0, 0); stB(0, 0, 0);
    stA(0, 1, 1); stB(0, 1, 1);
    stA(1, 0, 2); stB(1, 0, 2);

    for (int kt = 0; kt < 16; ++kt) {
        const int s0 = (2 * kt) & 3, s1 = (2 * kt + 1) & 3, sn = (2 * kt + 3) & 3;
        // ---- phase 0: ks=0, oh=0 ----
        if (kt < 15) asm volatile("s_waitcnt vmcnt(4)" ::: "memory");
        else         asm volatile("s_waitcnt vmcnt(0)" ::: "memory");
        __builtin_amdgcn_s_barrier();
        __builtin_amdgcn_sched_barrier(0);
        ldA(s0, 0); ldB(s0);
        if (kt < 15) stA(kt + 1, 1, sn);
        asm volatile("s_waitcnt lgkmcnt(0)" ::: "memory");
        __builtin_amdgcn_sched_barrier(0);
        mm(0);
        __builtin_amdgcn_s_barrier();
        __builtin_amdgcn_sched_barrier(0);
        // ---- phase 1: ks=0, oh=1 (reuse B frags) ----
        ldA(s0, 1);
        if (kt < 15) stB(kt + 1, 1, sn);
        asm volatile("s_waitcnt lgkmcnt(0)" ::: "memory");
        __builtin_amdgcn_sched_barrier(0);
        mm(4);
        __builtin_amdgcn_s_barrier();
        __builtin_amdgcn_sched_barrier(0);
        // ---- phase 2: ks=1, oh=0 ----
        ldA(s1, 0); ldB(s1);
        if (kt < 14) stA(kt + 2, 0, s0);
        asm volatile("s_waitcnt lgkmcnt(0)" ::: "memory");
        __builtin_amdgcn_sched_barrier(0);
        mm(0);
        __builtin_amdgcn_s_barrier();
        __builtin_amdgcn_sched_barrier(0);
        // ---- phase 3: ks=1, oh=1 ----
        ldA(s1, 1);
        if (kt < 14) stB(kt + 2, 0, s0);
        asm volatile("s_waitcnt lgkmcnt(0)" ::: "memory");
        __builtin_amdgcn_sched_barrier(0);
        mm(4);
        __builtin_amdgcn_s_barrier();
        __builtin_amdgcn_sched_barrier(0);
    }

    // ---- epilogue: C/D layout col=lane&15, row=(lane>>4)*4+reg ----
    #pragma unroll
    for (int j = 0; j < 4; ++j) {
        const int col = ncol0 + wc * 64 + j * 16 + lr;
        const float bz = bias[col];
        #pragma unroll
        for (int mi = 0; mi < 8; ++mi) {
            const int rb = m0 + wr * 128 + mi * 16 + lkq * 4;
            #pragma unroll
            for (int r = 0; r < 4; ++r) {
                const int row = rb + r;
                float v = acc[mi][j][r] + bz;
                if (z == 0) {
                    v = __expf(fminf(fmaxf(v, -60.f), 30.f));
                    ((float*)out)[(size_t)row * C_DIM + col] = v;
                } else if (z == 2) {
                    v = 1.f / (1.f + __expf(-v));
                    ((unsigned short*)out)[(size_t)row * C_DIM + col] = f2bf(v);
                } else {
                    ((unsigned short*)out)[(size_t)row * C_DIM + col] = f2bf(v);
                }
            }
        }
    }
}

// ---------------------------------------------------------------------------
// bf16 MFMA GEMM, BK=64, XOR-swizzled LDS (slot = chunk ^ (row&7)).
// Round-0 proven config: __launch_bounds__(256,2), 32 KiB LDS, VGPR 72.
// mode 3 only here: (v+bias)*gamma[t] -> fp32 out.
// Block swizzle: d -> y=((d&7)<<3)|((d>>3)&7), x=d>>6 (XCD L2 locality).
// ---------------------------------------------------------------------------
__global__ __launch_bounds__(256, 2)
void mfma_gemm64(const unsigned short* __restrict__ A,
                 const unsigned short* __restrict__ Wb,
                 const float* __restrict__ b0,
                 void* __restrict__ o0,
                 const float* __restrict__ gamma)
{
    const int d  = blockIdx.x;
    const int y  = ((d & 7) << 3) | ((d >> 3) & 7);
    const int xb = d >> 6;
    const int m0 = y * 128, n0 = xb * 128;

    __shared__ unsigned short As[128 * 64];
    __shared__ unsigned short Bs[128 * 64];

    const int tid = threadIdx.x;
    const int w = tid >> 6, l = tid & 63;

    const int r8  = l >> 3;
    const int c16 = ((l & 7) ^ r8) * 8;
    const unsigned short* gA = A  + (size_t)(m0 + w * 32 + r8) * C_DIM + c16;
    const unsigned short* gB = Wb + (size_t)(n0 + w * 32 + r8) * C_DIM + c16;
    char* lA = (char*)As + (w * 32) * 128;
    char* lB = (char*)Bs + (w * 32) * 128;

    const int wr = w >> 1, wc = w & 1;
    const int lr = l & 15, lkq = l >> 4;
    const int x7 = lr & 7;

    f32x4 acc[4][4];
    #pragma unroll
    for (int i = 0; i < 4; ++i)
        #pragma unroll
        for (int j = 0; j < 4; ++j) acc[i][j] = (f32x4){0.f, 0.f, 0.f, 0.f};

    for (int k0 = 0; k0 < C_DIM; k0 += 64) {
        #pragma unroll
        for (int r = 0; r < 4; ++r) {
            gld16(gA + k0 + (size_t)r * 8 * C_DIM, lA + r * 8 * 128);
            gld16(gB + k0 + (size_t)r * 8 * C_DIM, lB + r * 8 * 128);
        }
        __syncthreads();

        bf16x8 af[2][4], bfv[2][4];
        #pragma unroll
        for (int ks = 0; ks < 2; ++ks) {
            const int slot = ((ks * 4 + lkq) ^ x7) * 8;
            #pragma unroll
            for (int i = 0; i < 4; ++i)
                af[ks][i] = *(const bf16x8*)&As[(wr * 64 + i * 16 + lr) * 64 + slot];
            #pragma unroll
            for (int j = 0; j < 4; ++j)
                bfv[ks][j] = *(const bf16x8*)&Bs[(wc * 64 + j * 16 + lr) * 64 + slot];
        }
        #pragma unroll
        for (int ks = 0; ks < 2; ++ks)
            #pragma unroll
            for (int i = 0; i < 4; ++i)
                #pragma unroll
                for (int j = 0; j < 4; ++j)
                    acc[i][j] = __builtin_amdgcn_mfma_f32_16x16x32_bf16(
                        af[ks][i], bfv[ks][j], acc[i][j], 0, 0, 0);
        __syncthreads();
    }

    #pragma unroll
    for (int j = 0; j < 4; ++j) {
        const int col = n0 + wc * 64 + j * 16 + lr;
        const float bz = b0[col];
        #pragma unroll
        for (int i = 0; i < 4; ++i) {
            const int rb = m0 + wr * 64 + i * 16 + lkq * 4;
            #pragma unroll
            for (int r = 0; r < 4; ++r) {
                const int row = rb + r;
                float v = (acc[i][j][r] + bz) * gamma[row & (T_CTX - 1)];
                ((float*)o0)[(size_t)row * C_DIM + col] = v;
            }
        }
    }
}

// ---------------------------------------------------------------------------
// Chunk-local cumsum of expk + kvT[b,h,c,u] = bf16(expk * v * alpha[h,u]).
// ---------------------------------------------------------------------------
__global__ __launch_bounds__(256)
void cumsum_chunk(const float* __restrict__ expk, const unsigned short* __restrict__ vbf,
                  const float* __restrict__ alpha,
                  float* __restrict__ sumk, unsigned short* __restrict__ kvT,
                  float* __restrict__ aux)
{
    const int n = blockIdx.x * 256 + threadIdx.x;
    const int q = blockIdx.y;
    const int b = blockIdx.z;
    const int h = n >> 6, c = n & 63;
    const size_t base = ((size_t)b * T_CTX + q * 128) * C_DIM + n;
    unsigned short* kvrow = kvT + (((size_t)b * H_NUM + h) * HS + c) * T_CTX + q * 128;
    float s = 0.f;
    u16x8 buf;
    for (int i = 0; i < 128; ++i) {
        const size_t idx = base + (size_t)i * C_DIM;
        const float e  = expk[idx];
        const float vv = bf2f(vbf[idx]);
        const float a  = alpha[h * T_CTX + q * 128 + i];
        s += e;
        sumk[idx] = s;
        buf[i & 7] = f2bf(e * vv * a);
        if ((i & 7) == 7) *(u16x8*)(kvrow + i - 7) = buf;
    }
    aux[((size_t)b * 8 + q) * C_DIM + n] = s;
}

// ---------------------------------------------------------------------------
// wkv via MFMA (Toeplitz):  wkv[t,c] = sum_u twx[1023-t+u] * kvT[c,u]
// ---------------------------------------------------------------------------
#define REPL_STRIDE 1176
#define REPL_USED   1168

__global__ __launch_bounds__(256)
void wkv_mfma(const unsigned short* __restrict__ kvT,
              const float* __restrict__ sumk,
              const unsigned short* __restrict__ sigr,
              const float* __restrict__ tw, const float* __restrict__ beta,
              const float* __restrict__ aux,
              unsigned short* __restrict__ rwkv)
{
    __shared__ unsigned short repl[8 * REPL_STRIDE];
    __shared__ unsigned short kv_s[64 * 72];
    __shared__ unsigned short tw_s[1024];

    const int tid = threadIdx.x;
    const int bx = blockIdx.x;
    const int t0 = bx * 128;
    const int h  = blockIdx.y;
    const int b  = blockIdx.z;

    {
        const int i = tid * 4;
        const float4 v = *(const float4*)(tw + h * T_CTX + i);
        ushort4 o;
        o.x = f2bf(v.x); o.y = f2bf(v.y); o.z = f2bf(v.z); o.w = f2bf(v.w);
        *(ushort4*)&tw_s[i] = o;
    }
    __syncthreads();

    #pragma unroll
    for (int r = 0; r < 8; ++r)
        for (int i = tid; i < REPL_USED; i += 256) {
            const int src = i + r;
            repl[r * REPL_STRIDE + i] = (src < 1024) ? tw_s[src] : (unsigned short)0;
        }
    __syncthreads();

    const int w = tid >> 6, l = tid & 63;
    const int wr = w >> 1, wc = w & 1;
    const int lr = l & 15, lkq = l >> 4;

    const int r    = (7 - lr) & 7;
    const int S0   = 1023 - t0 - wr * 64 - lr + lkq * 8;
    const int abase = 2 * S0 + (2 * REPL_STRIDE - 2) * r;
    const char* repl_c = (const char*)repl;

    const int srow = tid >> 2;
    const int ucol = (tid & 3) * 16;
    const unsigned short* gkv = kvT + (((size_t)b * H_NUM + h) * HS + srow) * T_CTX + ucol;
    unsigned short* skv = &kv_s[srow * 72 + ucol];

    f32x4 acc[4][2];
    #pragma unroll
    for (int i = 0; i < 4; ++i) {
        acc[i][0] = (f32x4){0.f, 0.f, 0.f, 0.f};
        acc[i][1] = (f32x4){0.f, 0.f, 0.f, 0.f};
    }

    const int nsteps = t0 / 64 + 2;
    for (int ks = 0; ks < nsteps; ++ks) {
        const int u0 = ks * 64;
        const u16x8 q0 = *(const u16x8*)(gkv + u0);
        const u16x8 q1 = *(const u16x8*)(gkv + u0 + 8);
        __syncthreads();
        *(u16x8*)skv       = q0;
        *(u16x8*)(skv + 8) = q1;
        __syncthreads();

        const int ub = abase + 2 * u0;
        #pragma unroll
        for (int kk = 0; kk < 2; ++kk) {
            bf16x8 af[4], bfv[2];
            #pragma unroll
            for (int i = 0; i < 4; ++i)
                af[i] = *(const bf16x8*)(repl_c + (ub + kk * 64 - i * 32));
            #pragma unroll
            for (int j = 0; j < 2; ++j)
                bfv[j] = *(const bf16x8*)&kv_s[(wc * 32 + j * 16 + lr) * 72 + kk * 32 + lkq * 8];
            #pragma unroll
            for (int i = 0; i < 4; ++i)
                #pragma unroll
                for (int j = 0; j < 2; ++j)
                    acc[i][j] = __builtin_amdgcn_mfma_f32_16x16x32_bf16(
                        af[i], bfv[j], acc[i][j], 0, 0, 0);
        }
    }

    float off[2];
    #pragma unroll
    for (int j = 0; j < 2; ++j) {
        const int cl = wc * 32 + j * 16 + lr;
        float o = 0.f;
        for (int q = 0; q < bx; ++q)
            o += aux[((size_t)b * 8 + q) * C_DIM + h * HS + cl];
        off[j] = o;
    }

    #pragma unroll
    for (int i = 0; i < 4; ++i) {
        const int tb = t0 + wr * 64 + i * 16 + lkq * 4;
        #pragma unroll
        for (int rg = 0; rg < 4; ++rg) {
            const int t = tb + rg;
            const float bet = beta[h * T_CTX + t];
            const size_t row_off = ((size_t)(b * T_CTX + t)) * C_DIM + h * HS;
            #pragma unroll
            for (int j = 0; j < 2; ++j) {
                const int cl = wc * 32 + j * 16 + lr;
                const float sk = sumk[row_off + cl] + off[j];
                const float sr = bf2f(sigr[row_off + cl]);
                rwkv[row_off + cl] = f2bf(sr * bet * acc[i][j][rg] / sk);
            }
        }
    }
}

// ---------------------------------------------------------------------------
extern "C" void kernel_launch(void* const* d_in, const int* in_sizes, int n_in,
                              void* d_out, int out_size, void* d_ws, size_t ws_size,
                              hipStream_t stream)
{
    const float* x     = (const float*)d_in[0];
    const float* tw    = (const float*)d_in[1];
    const float* alpha = (const float*)d_in[2];
    const float* beta  = (const float*)d_in[3];
    const float* gamma = (const float*)d_in[4];
    const float* Wk    = (const float*)d_in[5];
    const float* bk    = (const float*)d_in[6];
    const float* Wv    = (const float*)d_in[7];
    const float* bv    = (const float*)d_in[8];
    const float* Wr    = (const float*)d_in[9];
    const float* br    = (const float*)d_in[10];
    const float* Wo    = (const float*)d_in[11];
    const float* bo    = (const float*)d_in[12];
    float* out = (float*)d_out;

    // workspace layout (bytes), max 128M:
    //  [0,32M)   expk fp32    -> rwkv bf16 [0,16M) after cumsum
    //  [32,48M)  v bf16
    //  [48,56M)  weights bf16 (Wk,Wv,Wr,Wo stacked @ 2MB each)
    //  [56,56.25M) aux (raw chunk totals)
    //  [64,96M)  sumk fp32 (chunk-local)  (xs bf16 overlays [64,80M) during proj)
    //  [96,112M) sigr bf16
    //  [112,128M) kvT bf16
    char* W = (char*)d_ws;
    float* expk          = (float*)W;
    unsigned short* rwkv = (unsigned short*)W;
    unsigned short* vbf  = (unsigned short*)(W + (32ull << 20));
    unsigned short* wbf  = (unsigned short*)(W + (48ull << 20));
    float* aux           = (float*)(W + (56ull << 20));
    float* sumk          = (float*)(W + (64ull << 20));
    unsigned short* xs   = (unsigned short*)(W + (64ull << 20));
    unsigned short* sigr = (unsigned short*)(W + (96ull << 20));
    unsigned short* kvT  = (unsigned short*)(W + (112ull << 20));

    const size_t WSZ = (size_t)C_DIM * C_DIM;

    convert_all<<<dim3(12288), 256, 0, stream>>>(x, xs, Wk, Wv, Wr, Wo, wbf);

    // k,v,r projections as one N=3072 GEMM (W stacked), 256x256 8-phase
    mfma_gemm256<<<dim3(384), 512, 0, stream>>>(
        xs, wbf, bk, bv, br, expk, vbf, sigr);

    cumsum_chunk<<<dim3(4, 8, 8), 256, 0, stream>>>(expk, vbf, alpha, sumk, kvT, aux);

    wkv_mfma<<<dim3(8, 16, 8), 256, 0, stream>>>(
        kvT, sumk, sigr, tw, beta, aux, rwkv);

    // output projection + gamma (round-0 proven 128^2 kernel)
    mfma_gemm64<<<dim3(512), 256, 0, stream>>>(
        rwkv, wbf + 3 * WSZ, bo, out, gamma);
}

// Round 4
// 277.179 us; speedup vs baseline: 1.0651x; 1.0651x over previous
//
#include <hip/hip_runtime.h>
#include <hip/hip_bf16.h>
#include <cstddef>
#include <cstdint>

#define B_SZ   8
#define T_CTX  1024
#define C_DIM  1024
#define H_NUM  16
#define HS     64
#define M_ROWS (B_SZ * T_CTX)

typedef __attribute__((ext_vector_type(8))) short bf16x8;
typedef __attribute__((ext_vector_type(8))) unsigned short u16x8;
typedef __attribute__((ext_vector_type(4))) float f32x4;

static __device__ inline unsigned short f2bf(float f) {
    __hip_bfloat16 h = __float2bfloat16(f);
    return __builtin_bit_cast(unsigned short, h);
}
static __device__ inline float bf2f(unsigned short u) {
    unsigned int v = ((unsigned int)u) << 16;
    return __builtin_bit_cast(float, v);
}
static __device__ inline void gld16(const void* g, void* l) {
    __builtin_amdgcn_global_load_lds((const __attribute__((address_space(1))) void*)g,
                                     (__attribute__((address_space(3))) void*)l,
                                     16, 0, 0);
}

// ---------------------------------------------------------------------------
// Fused conversion: blocks [0,8192) do x->xs (bf16, time-shifted);
// blocks [8192,12288) do the 4 weight matrices -> stacked bf16.
// ---------------------------------------------------------------------------
__global__ __launch_bounds__(256)
void convert_all(const float* __restrict__ x, unsigned short* __restrict__ xs,
                 const float* __restrict__ Wk, const float* __restrict__ Wv,
                 const float* __restrict__ Wr, const float* __restrict__ Wo,
                 unsigned short* __restrict__ wdst)
{
    const int bid = blockIdx.x;
    if (bid < 8192) {
        const int idx = (bid * 256 + threadIdx.x) * 4;
        const int m = idx >> 10;
        const int c = idx & 1023;
        float4 v;
        if (c < 512) {
            const int t = m & (T_CTX - 1);
            if (t == 0) v = make_float4(0.f, 0.f, 0.f, 0.f);
            else        v = *(const float4*)(x + (size_t)(m - 1) * C_DIM + c);
        } else {
            v = *(const float4*)(x + idx);
        }
        ushort4 o;
        o.x = f2bf(v.x); o.y = f2bf(v.y); o.z = f2bf(v.z); o.w = f2bf(v.w);
        *(ushort4*)(xs + idx) = o;
    } else {
        const int wid = bid - 8192;
        const int z = wid >> 10;
        const float* src = (z == 0) ? Wk : (z == 1) ? Wv : (z == 2) ? Wr : Wo;
        const int idx = ((wid & 1023) * 256 + threadIdx.x) * 4;
        const float4 v = *(const float4*)(src + idx);
        ushort4 o;
        o.x = f2bf(v.x); o.y = f2bf(v.y); o.z = f2bf(v.z); o.w = f2bf(v.w);
        *(ushort4*)(wdst + (size_t)z * (C_DIM * C_DIM) + idx) = o;
    }
}

// ---------------------------------------------------------------------------
// bf16 MFMA GEMM, BK=64, XOR-swizzled LDS (slot = chunk ^ (row&7)) to break
// the 16-way bank conflict of 128B-row fragment reads down to the b128
// 8-lane minimum.  Staging keeps gld16-contiguous writes; the lane->global
// chunk mapping carries the permutation.
// ROUND-0 PROVEN CONFIG: __launch_bounds__(256,2), 32 KiB LDS, VGPR 72,
// 75.4 us / 683 TF on the big GEMM.  (256,4) and 8-phase variants both
// regressed (rounds 1-3) — do not touch the sync structure.
// multi=1: W stacked [3072x1024]; mode = n0>>10:
//   0: exp(clip)->fp32 expk ; 1: identity->bf16 v ; 2: sigmoid->bf16 sigr
// multi=0: mode 3: (v+bias)*gamma[t] -> fp32 out
// Block swizzle: d -> y=((d&7)<<3)|((d>>3)&7), x=d>>6 (XCD L2 locality).
// ---------------------------------------------------------------------------
__global__ __launch_bounds__(256, 2)
void mfma_gemm64(const unsigned short* __restrict__ A,
                 const unsigned short* __restrict__ Wb,
                 const float* __restrict__ b0, const float* __restrict__ b1,
                 const float* __restrict__ b2,
                 void* __restrict__ o0, void* __restrict__ o1, void* __restrict__ o2,
                 const float* __restrict__ gamma, int multi)
{
    const int d  = blockIdx.x;
    const int y  = ((d & 7) << 3) | ((d >> 3) & 7);
    const int xb = d >> 6;
    const int m0 = y * 128, n0 = xb * 128;

    int mode, ncol0;
    const float* bias;
    void* out;
    if (multi) {
        const int z = n0 >> 10;
        mode = z;
        ncol0 = n0 & 1023;
        bias = (z == 0) ? b0 : (z == 1) ? b1 : b2;
        out  = (z == 0) ? o0 : (z == 1) ? o1 : o2;
    } else {
        mode = 3; ncol0 = n0; bias = b0; out = o0;
    }

    __shared__ unsigned short As[128 * 64];
    __shared__ unsigned short Bs[128 * 64];

    const int tid = threadIdx.x;
    const int w = tid >> 6, l = tid & 63;

    // staging: wave w covers rows [w*32, w*32+32) in 4 rounds of 8 rows.
    // lane l -> row offset r8 = l>>3, fetches global k-chunk (l&7)^r8 so the
    // contiguous LDS write leaves slot s of row R holding chunk s^(R&7).
    const int r8  = l >> 3;
    const int c16 = ((l & 7) ^ r8) * 8;
    const unsigned short* gA = A  + (size_t)(m0 + w * 32 + r8) * C_DIM + c16;
    const unsigned short* gB = Wb + (size_t)(n0 + w * 32 + r8) * C_DIM + c16;
    char* lA = (char*)As + (w * 32) * 128;
    char* lB = (char*)Bs + (w * 32) * 128;

    const int wr = w >> 1, wc = w & 1;
    const int lr = l & 15, lkq = l >> 4;
    const int x7 = lr & 7;

    f32x4 acc[4][4];
    #pragma unroll
    for (int i = 0; i < 4; ++i)
        #pragma unroll
        for (int j = 0; j < 4; ++j) acc[i][j] = (f32x4){0.f, 0.f, 0.f, 0.f};

    for (int k0 = 0; k0 < C_DIM; k0 += 64) {
        #pragma unroll
        for (int r = 0; r < 4; ++r) {
            gld16(gA + k0 + (size_t)r * 8 * C_DIM, lA + r * 8 * 128);
            gld16(gB + k0 + (size_t)r * 8 * C_DIM, lB + r * 8 * 128);
        }
        __syncthreads();

        bf16x8 af[2][4], bfv[2][4];
        #pragma unroll
        for (int ks = 0; ks < 2; ++ks) {
            const int slot = ((ks * 4 + lkq) ^ x7) * 8;   // swizzled k-offset
            #pragma unroll
            for (int i = 0; i < 4; ++i)
                af[ks][i] = *(const bf16x8*)&As[(wr * 64 + i * 16 + lr) * 64 + slot];
            #pragma unroll
            for (int j = 0; j < 4; ++j)
                bfv[ks][j] = *(const bf16x8*)&Bs[(wc * 64 + j * 16 + lr) * 64 + slot];
        }
        #pragma unroll
        for (int ks = 0; ks < 2; ++ks)
            #pragma unroll
            for (int i = 0; i < 4; ++i)
                #pragma unroll
                for (int j = 0; j < 4; ++j)
                    acc[i][j] = __builtin_amdgcn_mfma_f32_16x16x32_bf16(
                        af[ks][i], bfv[ks][j], acc[i][j], 0, 0, 0);
        __syncthreads();
    }

    // epilogue: C/D layout col=lane&15, row=(lane>>4)*4+reg
    #pragma unroll
    for (int j = 0; j < 4; ++j) {
        const int col = ncol0 + wc * 64 + j * 16 + lr;
        const float bz = bias[col];
        #pragma unroll
        for (int i = 0; i < 4; ++i) {
            const int rb = m0 + wr * 64 + i * 16 + lkq * 4;
            #pragma unroll
            for (int r = 0; r < 4; ++r) {
                const int row = rb + r;
                float v = acc[i][j][r] + bz;
                if (mode == 0)      v = __expf(fminf(fmaxf(v, -60.f), 30.f));
                else if (mode == 2) v = 1.f / (1.f + __expf(-v));
                else if (mode == 3) v *= gamma[row & (T_CTX - 1)];
                if (mode == 1 || mode == 2)
                    ((unsigned short*)out)[(size_t)row * C_DIM + col] = f2bf(v);
                else
                    ((float*)out)[(size_t)row * C_DIM + col] = v;
            }
        }
    }
}

// ---------------------------------------------------------------------------
// Chunk-local cumsum of expk + kvT[b,h,c,u] = bf16(expk * v * alpha[h,u]).
// 64-row chunks (q = blockIdx.y in [0,16)): doubles wave count vs 128-row
// (2 waves/SIMD) and halves the serial scan.  Inner 8-group is fully
// unrolled with STATIC u16x8 indices (rule #20: runtime-indexed ext_vector
// goes to scratch) and gives 8-deep load MLP.
// sumk holds CHUNK-LOCAL prefix sums; aux[b,q,n] = raw 64-chunk totals.
// ---------------------------------------------------------------------------
__global__ __launch_bounds__(256)
void cumsum_chunk(const float* __restrict__ expk, const unsigned short* __restrict__ vbf,
                  const float* __restrict__ alpha,
                  float* __restrict__ sumk, unsigned short* __restrict__ kvT,
                  float* __restrict__ aux)
{
    const int n = blockIdx.x * 256 + threadIdx.x;
    const int q = blockIdx.y;            // 16 chunks of 64 rows
    const int b = blockIdx.z;
    const int h = n >> 6, c = n & 63;
    const size_t base = ((size_t)b * T_CTX + q * 64) * C_DIM + n;
    unsigned short* kvrow = kvT + (((size_t)b * H_NUM + h) * HS + c) * T_CTX + q * 64;
    const float* arow = alpha + h * T_CTX + q * 64;
    float s = 0.f;
    for (int g = 0; g < 8; ++g) {
        u16x8 buf;
        #pragma unroll
        for (int k = 0; k < 8; ++k) {
            const int i = g * 8 + k;
            const size_t idx = base + (size_t)i * C_DIM;
            const float e  = expk[idx];
            const float vv = bf2f(vbf[idx]);
            s += e;
            sumk[idx] = s;
            buf[k] = f2bf(e * vv * arow[i]);
        }
        *(u16x8*)(kvrow + g * 8) = buf;
    }
    aux[((size_t)b * 16 + q) * C_DIM + n] = s;
}

// ---------------------------------------------------------------------------
// wkv via MFMA (Toeplitz):  wkv[t,c] = sum_u twx[1023-t+u] * kvT[c,u]
// A-frags from 8 shift-replicas of twx in LDS; B = kvT tile in padded LDS.
// Epilogue: rwkv = sigr * beta[t] * acc / (sumk_chunk + prefix(aux))  (bf16)
// 64-row sumk chunks: each thread's 4 output rows (tb..tb+3, tb mod 64 <= 60)
// lie entirely in chunk (2*bx + wr), so the aux prefix bound is 2*bx+wr.
// Global K/V loads are software-pipelined one step ahead (issued before the
// MFMA cluster) so HBM/L2 latency hides under compute.
// ---------------------------------------------------------------------------
#define REPL_STRIDE 1176
#define REPL_USED   1168

__global__ __launch_bounds__(256)
void wkv_mfma(const unsigned short* __restrict__ kvT,
              const float* __restrict__ sumk,
              const unsigned short* __restrict__ sigr,
              const float* __restrict__ tw, const float* __restrict__ beta,
              const float* __restrict__ aux,
              unsigned short* __restrict__ rwkv)
{
    __shared__ unsigned short repl[8 * REPL_STRIDE];
    __shared__ unsigned short kv_s[64 * 72];
    __shared__ unsigned short tw_s[1024];

    const int tid = threadIdx.x;
    const int bx = blockIdx.x;
    const int t0 = bx * 128;
    const int h  = blockIdx.y;
    const int b  = blockIdx.z;

    {
        const int i = tid * 4;
        const float4 v = *(const float4*)(tw + h * T_CTX + i);
        ushort4 o;
        o.x = f2bf(v.x); o.y = f2bf(v.y); o.z = f2bf(v.z); o.w = f2bf(v.w);
        *(ushort4*)&tw_s[i] = o;
    }
    __syncthreads();

    #pragma unroll
    for (int r = 0; r < 8; ++r)
        for (int i = tid; i < REPL_USED; i += 256) {
            const int src = i + r;
            repl[r * REPL_STRIDE + i] = (src < 1024) ? tw_s[src] : (unsigned short)0;
        }
    __syncthreads();

    const int w = tid >> 6, l = tid & 63;
    const int wr = w >> 1, wc = w & 1;
    const int lr = l & 15, lkq = l >> 4;

    const int r    = (7 - lr) & 7;
    const int S0   = 1023 - t0 - wr * 64 - lr + lkq * 8;
    const int abase = 2 * S0 + (2 * REPL_STRIDE - 2) * r;
    const char* repl_c = (const char*)repl;

    const int srow = tid >> 2;
    const int ucol = (tid & 3) * 16;
    const unsigned short* gkv = kvT + (((size_t)b * H_NUM + h) * HS + srow) * T_CTX + ucol;
    unsigned short* skv = &kv_s[srow * 72 + ucol];

    f32x4 acc[4][2];
    #pragma unroll
    for (int i = 0; i < 4; ++i) {
        acc[i][0] = (f32x4){0.f, 0.f, 0.f, 0.f};
        acc[i][1] = (f32x4){0.f, 0.f, 0.f, 0.f};
    }

    const int nsteps = t0 / 64 + 2;
    u16x8 q0 = *(const u16x8*)(gkv);
    u16x8 q1 = *(const u16x8*)(gkv + 8);
    for (int ks = 0; ks < nsteps; ++ks) {
        __syncthreads();
        *(u16x8*)skv       = q0;
        *(u16x8*)(skv + 8) = q1;
        __syncthreads();
        if (ks + 1 < nsteps) {
            const int un = (ks + 1) * 64;
            q0 = *(const u16x8*)(gkv + un);
            q1 = *(const u16x8*)(gkv + un + 8);
        }

        const int ub = abase + 2 * (ks * 64);
        #pragma unroll
        for (int kk = 0; kk < 2; ++kk) {
            bf16x8 af[4], bfv[2];
            #pragma unroll
            for (int i = 0; i < 4; ++i)
                af[i] = *(const bf16x8*)(repl_c + (ub + kk * 64 - i * 32));
            #pragma unroll
            for (int j = 0; j < 2; ++j)
                bfv[j] = *(const bf16x8*)&kv_s[(wc * 32 + j * 16 + lr) * 72 + kk * 32 + lkq * 8];
            #pragma unroll
            for (int i = 0; i < 4; ++i)
                #pragma unroll
                for (int j = 0; j < 2; ++j)
                    acc[i][j] = __builtin_amdgcn_mfma_f32_16x16x32_bf16(
                        af[i], bfv[j], acc[i][j], 0, 0, 0);
        }
    }

    // aux prefix: this thread's rows live in 64-chunk (2*bx + wr)
    const int cq = 2 * bx + wr;
    float off[2];
    #pragma unroll
    for (int j = 0; j < 2; ++j) {
        const int cl = wc * 32 + j * 16 + lr;
        float o = 0.f;
        for (int q = 0; q < cq; ++q)
            o += aux[((size_t)b * 16 + q) * C_DIM + h * HS + cl];
        off[j] = o;
    }

    #pragma unroll
    for (int i = 0; i < 4; ++i) {
        const int tb = t0 + wr * 64 + i * 16 + lkq * 4;
        #pragma unroll
        for (int rg = 0; rg < 4; ++rg) {
            const int t = tb + rg;
            const float bet = beta[h * T_CTX + t];
            const size_t row_off = ((size_t)(b * T_CTX + t)) * C_DIM + h * HS;
            #pragma unroll
            for (int j = 0; j < 2; ++j) {
                const int cl = wc * 32 + j * 16 + lr;
                const float sk = sumk[row_off + cl] + off[j];
                const float sr = bf2f(sigr[row_off + cl]);
                rwkv[row_off + cl] = f2bf(sr * bet * acc[i][j][rg] / sk);
            }
        }
    }
}

// ---------------------------------------------------------------------------
extern "C" void kernel_launch(void* const* d_in, const int* in_sizes, int n_in,
                              void* d_out, int out_size, void* d_ws, size_t ws_size,
                              hipStream_t stream)
{
    const float* x     = (const float*)d_in[0];
    const float* tw    = (const float*)d_in[1];
    const float* alpha = (const float*)d_in[2];
    const float* beta  = (const float*)d_in[3];
    const float* gamma = (const float*)d_in[4];
    const float* Wk    = (const float*)d_in[5];
    const float* bk    = (const float*)d_in[6];
    const float* Wv    = (const float*)d_in[7];
    const float* bv    = (const float*)d_in[8];
    const float* Wr    = (const float*)d_in[9];
    const float* br    = (const float*)d_in[10];
    const float* Wo    = (const float*)d_in[11];
    const float* bo    = (const float*)d_in[12];
    float* out = (float*)d_out;

    // workspace layout (bytes), max 128M:
    //  [0,32M)   expk fp32    -> rwkv bf16 [0,16M) after cumsum
    //  [32,48M)  v bf16
    //  [48,56M)  weights bf16 (Wk,Wv,Wr,Wo stacked @ 2MB each)
    //  [56,56.5M) aux (raw 64-chunk totals, 8*16*1024*4B = 512KB)
    //  [64,96M)  sumk fp32 (chunk-local)  (xs bf16 overlays [64,80M) during proj)
    //  [96,112M) sigr bf16
    //  [112,128M) kvT bf16
    char* W = (char*)d_ws;
    float* expk          = (float*)W;
    unsigned short* rwkv = (unsigned short*)W;
    unsigned short* vbf  = (unsigned short*)(W + (32ull << 20));
    unsigned short* wbf  = (unsigned short*)(W + (48ull << 20));
    float* aux           = (float*)(W + (56ull << 20));
    float* sumk          = (float*)(W + (64ull << 20));
    unsigned short* xs   = (unsigned short*)(W + (64ull << 20));
    unsigned short* sigr = (unsigned short*)(W + (96ull << 20));
    unsigned short* kvT  = (unsigned short*)(W + (112ull << 20));

    const size_t WSZ = (size_t)C_DIM * C_DIM;

    convert_all<<<dim3(12288), 256, 0, stream>>>(x, xs, Wk, Wv, Wr, Wo, wbf);

    // k,v,r projections as one N=3072 GEMM (W stacked), XCD-swizzled
    mfma_gemm64<<<dim3(1536), 256, 0, stream>>>(
        xs, wbf, bk, bv, br, expk, vbf, sigr, gamma, 1);

    cumsum_chunk<<<dim3(4, 16, 8), 256, 0, stream>>>(expk, vbf, alpha, sumk, kvT, aux);

    wkv_mfma<<<dim3(8, 16, 8), 256, 0, stream>>>(
        kvT, sumk, sigr, tw, beta, aux, rwkv);

    // output projection + gamma
    mfma_gemm64<<<dim3(512), 256, 0, stream>>>(
        rwkv, wbf + 3 * WSZ, bo, nullptr, nullptr,
        out, nullptr, nullptr, gamma, 0);
}